// Round 11
// baseline (387.162 us; speedup 1.0000x reference)
//
#include <hip/hip_runtime.h>

#define C_IN 256
#define C_OUT 64
#define BSH 7                 // bucket = dst >> 7  (128 nodes/bucket)
#define NPB 128               // nodes per bucket
#define NB 1024               // max buckets (n <= 131072)
#define CHUNK 4096            // edges per binning block
#define ROWS 4                // table rows per thread in kA2 (256*4 >= nbin)
#define CAPL 4736             // LDS edge capacity per bucket (proven bound: R7 passed with CAP=4736)
#define LDK 264               // padded row stride (ushorts): 256 + 8 -> 528 B

typedef short bf16x8 __attribute__((ext_vector_type(8)));
typedef float f32x4 __attribute__((ext_vector_type(4)));

__device__ __forceinline__ unsigned short f2bf(float f) {
    unsigned u = __builtin_bit_cast(unsigned, f);
    u = (u + 0x7FFFu + ((u >> 16) & 1u)) >> 16;
    return (unsigned short)u;
}
__device__ __forceinline__ float bflo(unsigned u) {
    return __builtin_bit_cast(float, u << 16);
}
__device__ __forceinline__ float bfhi(unsigned u) {
    return __builtin_bit_cast(float, u & 0xffff0000u);
}

// ---------------- per-(block,bucket) histogram table ----------------
__global__ __launch_bounds__(256) void k_hist2(const int* __restrict__ dst,
                                               int* __restrict__ table, int e) {
    __shared__ int cnt[NB];
    for (int j = threadIdx.x; j < NB; j += 256) cnt[j] = 0;
    __syncthreads();
    int b0 = blockIdx.x * CHUNK;
#pragma unroll 4
    for (int k = 0; k < CHUNK / 256; ++k) {
        int i = b0 + k * 256 + threadIdx.x;
        if (i < e) atomicAdd(&cnt[dst[i] >> BSH], 1);
    }
    __syncthreads();
    int* row = table + (size_t)blockIdx.x * NB;
    for (int j = threadIdx.x; j < NB; j += 256) row[j] = cnt[j];
}

// ---------------- column-wise exclusive scan: one block per bucket ----------------
__global__ __launch_bounds__(256) void kA2(int* __restrict__ table,
                                           int* __restrict__ tot, int nbin) {
    __shared__ int part[256];
    int bucket = blockIdx.x;
    int t = threadIdx.x;
    int v[ROWS];
    int s = 0;
#pragma unroll
    for (int i = 0; i < ROWS; ++i) {
        int r = t * ROWS + i;
        int x = (r < nbin) ? table[(size_t)r * NB + bucket] : 0;
        v[i] = s;
        s += x;
    }
    part[t] = s;
    __syncthreads();
    for (int off = 1; off < 256; off <<= 1) {
        int u = (t >= off) ? part[t - off] : 0;
        __syncthreads();
        part[t] += u;
        __syncthreads();
    }
    int base = part[t] - s;  // exclusive over threads
#pragma unroll
    for (int i = 0; i < ROWS; ++i) {
        int r = t * ROWS + i;
        if (r < nbin) table[(size_t)r * NB + bucket] = v[i] + base;
    }
    if (t == 255) tot[bucket] = part[255];
}

// ---------------- bucket totals -> compact gbase ----------------
__global__ __launch_bounds__(1024) void kB(const int* __restrict__ tot,
                                           int* __restrict__ gbase, int e) {
    __shared__ int l[NB];
    int t = threadIdx.x;
    int v = tot[t];
    l[t] = v;
    __syncthreads();
    for (int off = 1; off < NB; off <<= 1) {
        int u = (t >= off) ? l[t - off] : 0;
        __syncthreads();
        l[t] += u;
        __syncthreads();
    }
    gbase[t] = l[t] - v;  // exclusive
    if (t == NB - 1) gbase[NB] = e;
}

// ---------------- single-pass atomic-free multisplit ----------------
__global__ __launch_bounds__(256) void k_bin2(const int* __restrict__ src,
                                              const int* __restrict__ dst,
                                              const int* __restrict__ table,
                                              const int* __restrict__ gbase,
                                              int* __restrict__ sorted, int e) {
    __shared__ int cur[NB];
    const int* row = table + (size_t)blockIdx.x * NB;
    for (int j = threadIdx.x; j < NB; j += 256) cur[j] = row[j] + gbase[j];
    __syncthreads();
    int b0 = blockIdx.x * CHUNK;
#pragma unroll 4
    for (int k = 0; k < CHUNK / 256; ++k) {
        int i = b0 + k * 256 + threadIdx.x;
        if (i < e) {
            int d = dst[i];
            int bb = d >> BSH;
            int off = atomicAdd(&cur[bb], 1);
            sorted[off] = (src[i] << BSH) | (d & (NPB - 1));
        }
    }
}

// ---------------- per-node degree -> dinv (one block per bucket) ----------------
__global__ __launch_bounds__(256) void k_deg(const int* __restrict__ sorted,
                                             const int* __restrict__ gbase,
                                             float* __restrict__ dinv, int n) {
    __shared__ int cnt[NPB];
    int b = blockIdx.x;
    int node0 = b * NPB;
    int range = min(NPB, n - node0);
    int inbase = gbase[b];
    int m_b = gbase[b + 1] - inbase;
    if (threadIdx.x < NPB) cnt[threadIdx.x] = 0;
    __syncthreads();
    for (int j = threadIdx.x; j < m_b; j += 256)
        atomicAdd(&cnt[sorted[inbase + j] & (NPB - 1)], 1);
    __syncthreads();
    if (threadIdx.x < range)
        dinv[node0 + threadIdx.x] = rsqrtf((float)(cnt[threadIdx.x] + 1));
}

// ---------------- h' = (x @ W) * dinv[row], bf16 MFMA ----------------
__global__ __launch_bounds__(256) void k_gemm(const float* __restrict__ x,
                                              const float* __restrict__ W,
                                              const float* __restrict__ dinv,
                                              unsigned short* __restrict__ h, int n) {
    __shared__ unsigned short Xl[64 * LDK];
    __shared__ unsigned short Wl[64 * LDK];  // transposed: Wl[n][k]

    const int t = threadIdx.x;
    const int row0 = blockIdx.x * 64;

#pragma unroll
    for (int i = 0; i < 16; ++i) {
        int f = i * 256 + t;
        int k = f >> 4;
        int n4 = (f & 15) * 4;
        float4 v = ((const float4*)W)[f];
        Wl[(n4 + 0) * LDK + k] = f2bf(v.x);
        Wl[(n4 + 1) * LDK + k] = f2bf(v.y);
        Wl[(n4 + 2) * LDK + k] = f2bf(v.z);
        Wl[(n4 + 3) * LDK + k] = f2bf(v.w);
    }
#pragma unroll
    for (int i = 0; i < 16; ++i) {
        int f = i * 256 + t;
        int row = f >> 6;
        int c4 = f & 63;
        int gr = row0 + row;
        float4 v = (gr < n) ? ((const float4*)x)[(size_t)gr * 64 + c4]
                            : make_float4(0.f, 0.f, 0.f, 0.f);
        unsigned short* p = &Xl[row * LDK + c4 * 4];
        ushort4 o;
        o.x = f2bf(v.x); o.y = f2bf(v.y); o.z = f2bf(v.z); o.w = f2bf(v.w);
        *(ushort4*)p = o;
    }
    __syncthreads();

    const int lane = t & 63;
    const int w = t >> 6;
    const int m = lane & 15;
    const int q = lane >> 4;

    f32x4 acc[4];
#pragma unroll
    for (int nt = 0; nt < 4; ++nt) acc[nt] = (f32x4){0.f, 0.f, 0.f, 0.f};

#pragma unroll
    for (int ks = 0; ks < 8; ++ks) {
        bf16x8 A = *(const bf16x8*)&Xl[(16 * w + m) * LDK + ks * 32 + q * 8];
#pragma unroll
        for (int nt = 0; nt < 4; ++nt) {
            bf16x8 B = *(const bf16x8*)&Wl[(16 * nt + m) * LDK + ks * 32 + q * 8];
            acc[nt] = __builtin_amdgcn_mfma_f32_16x16x32_bf16(A, B, acc[nt], 0, 0, 0);
        }
    }

#pragma unroll
    for (int r = 0; r < 4; ++r) {
        int gr = row0 + 16 * w + q * 4 + r;
        if (gr < n) {
            float di = dinv[gr];
#pragma unroll
            for (int nt = 0; nt < 4; ++nt)
                h[(size_t)gr * C_OUT + nt * 16 + m] = f2bf(acc[nt][r] * di);
        }
    }
}

// ---------------- fused in-LDS sort + gather (one block per bucket) ----------------
// out[d] = di_d * (sum_{s in N(d)} h'[s] + h'[d]) + b,  h' = (xW)*dinv
__global__ __launch_bounds__(256) void k_sg(const int* __restrict__ sorted,
                                            const int* __restrict__ gbase,
                                            const unsigned short* __restrict__ h,
                                            const float* __restrict__ bias,
                                            float* __restrict__ out, int n) {
    __shared__ int cnt[NPB];
    __shared__ int sc[NPB];
    __shared__ int cur[NPB];
    __shared__ int eidx_l[CAPL];

    int b = blockIdx.x;
    int node0 = b * NPB;
    int range = min(NPB, n - node0);
    int inbase = gbase[b];
    int m_b = gbase[b + 1] - inbase;

    if (threadIdx.x < NPB) cnt[threadIdx.x] = 0;
    __syncthreads();
    for (int j = threadIdx.x; j < m_b; j += 256)
        atomicAdd(&cnt[sorted[inbase + j] & (NPB - 1)], 1);
    __syncthreads();
    if (threadIdx.x < NPB) sc[threadIdx.x] = cnt[threadIdx.x];
    __syncthreads();
    for (int off = 1; off < NPB; off <<= 1) {
        int t = (threadIdx.x < NPB && threadIdx.x >= off) ? sc[threadIdx.x - off] : 0;
        __syncthreads();
        if (threadIdx.x < NPB) sc[threadIdx.x] += t;
        __syncthreads();
    }
    if (threadIdx.x < NPB) cur[threadIdx.x] = sc[threadIdx.x] - cnt[threadIdx.x];
    __syncthreads();
    for (int j = threadIdx.x; j < m_b; j += 256) {
        int v = sorted[inbase + j];
        int pos = atomicAdd(&cur[v & (NPB - 1)], 1);
        eidx_l[pos] = v >> BSH;
    }
    __syncthreads();

    // gather: wave per node, quarter-wave per edge, 4 ch/lane
    int w = threadIdx.x >> 6;
    int lane = threadIdx.x & 63;
    int q = lane >> 4;
    int c4 = (lane & 15) * 4;

    for (int loc = w; loc < range; loc += 4) {
        int end = sc[loc];
        int beg = end - cnt[loc];
        float a0 = 0.f, a1 = 0.f, a2 = 0.f, a3 = 0.f;
        int j = beg;
        for (; j + 7 < end; j += 8) {
            int sa = eidx_l[j + q];
            int sb = eidx_l[j + 4 + q];
            uint2 ha = *(const uint2*)&h[(size_t)sa * C_OUT + c4];
            uint2 hb = *(const uint2*)&h[(size_t)sb * C_OUT + c4];
            a0 += bflo(ha.x); a1 += bfhi(ha.x);
            a2 += bflo(ha.y); a3 += bfhi(ha.y);
            a0 += bflo(hb.x); a1 += bfhi(hb.x);
            a2 += bflo(hb.y); a3 += bfhi(hb.y);
        }
        for (; j < end; j += 4) {
            int rem = end - j;
            int idx = j + ((q < rem) ? q : 0);
            int s = eidx_l[idx];
            float mq = (q < rem) ? 1.f : 0.f;
            uint2 hv = *(const uint2*)&h[(size_t)s * C_OUT + c4];
            a0 += bflo(hv.x) * mq; a1 += bfhi(hv.x) * mq;
            a2 += bflo(hv.y) * mq; a3 += bfhi(hv.y) * mq;
        }
        a0 += __shfl_xor(a0, 16, 64); a0 += __shfl_xor(a0, 32, 64);
        a1 += __shfl_xor(a1, 16, 64); a1 += __shfl_xor(a1, 32, 64);
        a2 += __shfl_xor(a2, 16, 64); a2 += __shfl_xor(a2, 32, 64);
        a3 += __shfl_xor(a3, 16, 64); a3 += __shfl_xor(a3, 32, 64);
        if (q == 0) {
            int node = node0 + loc;
            float di = rsqrtf((float)(cnt[loc] + 1));
            uint2 sv = *(const uint2*)&h[(size_t)node * C_OUT + c4];
            float4 bb = *(const float4*)&bias[c4];
            float4 o;
            o.x = (a0 + bflo(sv.x)) * di + bb.x;
            o.y = (a1 + bfhi(sv.x)) * di + bb.y;
            o.z = (a2 + bflo(sv.y)) * di + bb.z;
            o.w = (a3 + bfhi(sv.y)) * di + bb.w;
            *(float4*)&out[(size_t)node * C_OUT + c4] = o;
        }
    }
}

extern "C" void kernel_launch(void* const* d_in, const int* in_sizes, int n_in,
                              void* d_out, int out_size, void* d_ws, size_t ws_size,
                              hipStream_t stream) {
    const float* x = (const float*)d_in[0];
    const int* ei = (const int*)d_in[1];
    const float* W = (const float*)d_in[2];
    const float* bias = (const float*)d_in[3];
    float* out = (float*)d_out;

    const int n = in_sizes[0] / C_IN;  // 100000
    const int e = in_sizes[1] / 2;     // 3200000
    const int* src = ei;
    const int* dst = ei + e;

    const int nbin = (e + CHUNK - 1) / CHUNK;   // 782
    const int nbuck = (n + NPB - 1) / NPB;      // 782

    char* w = (char*)d_ws;
    unsigned short* h = (unsigned short*)w;  w += (size_t)n * C_OUT * 2;   // 12.8 MB
    int* sorted = (int*)w;                   w += (size_t)e * 4;           // 12.8 MB
    float* dinv = (float*)w;                 w += (size_t)n * 4;
    int* table = (int*)w;                    w += (size_t)nbin * NB * 4;   // 3.2 MB
    int* tot = (int*)w;                      w += NB * 4;
    int* gbase = (int*)w;                    w += (NB + 1) * 4;

    k_hist2<<<nbin, 256, 0, stream>>>(dst, table, e);
    kA2<<<NB, 256, 0, stream>>>(table, tot, nbin);
    kB<<<1, 1024, 0, stream>>>(tot, gbase, e);
    k_bin2<<<nbin, 256, 0, stream>>>(src, dst, table, gbase, sorted, e);
    k_deg<<<nbuck, 256, 0, stream>>>(sorted, gbase, dinv, n);
    k_gemm<<<(n + 63) / 64, 256, 0, stream>>>(x, W, dinv, h, n);
    k_sg<<<nbuck, 256, 0, stream>>>(sorted, gbase, h, bias, out, n);
}

// Round 12
// 364.575 us; speedup vs baseline: 1.0620x; 1.0620x over previous
//
#include <hip/hip_runtime.h>

#define C_IN 256
#define C_OUT 64
#define BSH 7                 // bucket = dst >> 7  (128 nodes/bucket)
#define NPB 128               // nodes per bucket
#define NB 1024               // max buckets (n <= 131072)
#define CHUNK 4096            // edges per binning block
#define ROWS 4                // table rows per thread in kA2 (256*4 >= nbin)
#define LDK 264               // padded row stride (ushorts): 256 + 8 -> 528 B

typedef short bf16x8 __attribute__((ext_vector_type(8)));
typedef float f32x4 __attribute__((ext_vector_type(4)));

__device__ __forceinline__ unsigned short f2bf(float f) {
    unsigned u = __builtin_bit_cast(unsigned, f);
    u = (u + 0x7FFFu + ((u >> 16) & 1u)) >> 16;
    return (unsigned short)u;
}
__device__ __forceinline__ float bflo(unsigned u) {
    return __builtin_bit_cast(float, u << 16);
}
__device__ __forceinline__ float bfhi(unsigned u) {
    return __builtin_bit_cast(float, u & 0xffff0000u);
}

// ---------------- per-(block,bucket) histogram table ----------------
__global__ __launch_bounds__(256) void k_hist2(const int* __restrict__ dst,
                                               int* __restrict__ table, int e) {
    __shared__ int cnt[NB];
    for (int j = threadIdx.x; j < NB; j += 256) cnt[j] = 0;
    __syncthreads();
    int b0 = blockIdx.x * CHUNK;
#pragma unroll 4
    for (int k = 0; k < CHUNK / 256; ++k) {
        int i = b0 + k * 256 + threadIdx.x;
        if (i < e) atomicAdd(&cnt[dst[i] >> BSH], 1);
    }
    __syncthreads();
    int* row = table + (size_t)blockIdx.x * NB;
    for (int j = threadIdx.x; j < NB; j += 256) row[j] = cnt[j];
}

// ---------------- column-wise exclusive scan: one block per bucket ----------------
__global__ __launch_bounds__(256) void kA2(int* __restrict__ table,
                                           int* __restrict__ tot, int nbin) {
    __shared__ int part[256];
    int bucket = blockIdx.x;
    int t = threadIdx.x;
    int v[ROWS];
    int s = 0;
#pragma unroll
    for (int i = 0; i < ROWS; ++i) {
        int r = t * ROWS + i;
        int x = (r < nbin) ? table[(size_t)r * NB + bucket] : 0;
        v[i] = s;
        s += x;
    }
    part[t] = s;
    __syncthreads();
    for (int off = 1; off < 256; off <<= 1) {
        int u = (t >= off) ? part[t - off] : 0;
        __syncthreads();
        part[t] += u;
        __syncthreads();
    }
    int base = part[t] - s;  // exclusive over threads
#pragma unroll
    for (int i = 0; i < ROWS; ++i) {
        int r = t * ROWS + i;
        if (r < nbin) table[(size_t)r * NB + bucket] = v[i] + base;
    }
    if (t == 255) tot[bucket] = part[255];
}

// ---------------- bucket totals -> compact gbase ----------------
__global__ __launch_bounds__(1024) void kB(const int* __restrict__ tot,
                                           int* __restrict__ gbase, int e) {
    __shared__ int l[NB];
    int t = threadIdx.x;
    int v = tot[t];
    l[t] = v;
    __syncthreads();
    for (int off = 1; off < NB; off <<= 1) {
        int u = (t >= off) ? l[t - off] : 0;
        __syncthreads();
        l[t] += u;
        __syncthreads();
    }
    gbase[t] = l[t] - v;  // exclusive
    if (t == NB - 1) gbase[NB] = e;
}

// ---------------- single-pass atomic-free multisplit ----------------
__global__ __launch_bounds__(256) void k_bin2(const int* __restrict__ src,
                                              const int* __restrict__ dst,
                                              const int* __restrict__ table,
                                              const int* __restrict__ gbase,
                                              int* __restrict__ sorted, int e) {
    __shared__ int cur[NB];
    const int* row = table + (size_t)blockIdx.x * NB;
    for (int j = threadIdx.x; j < NB; j += 256) cur[j] = row[j] + gbase[j];
    __syncthreads();
    int b0 = blockIdx.x * CHUNK;
#pragma unroll 4
    for (int k = 0; k < CHUNK / 256; ++k) {
        int i = b0 + k * 256 + threadIdx.x;
        if (i < e) {
            int d = dst[i];
            int bb = d >> BSH;
            int off = atomicAdd(&cur[bb], 1);
            sorted[off] = (src[i] << BSH) | (d & (NPB - 1));
        }
    }
}

// ---------------- in-bucket counting sort -> per-node CSR, plus dinv ----------------
__global__ __launch_bounds__(256) void k_sort2(const int* __restrict__ sorted,
                                               const int* __restrict__ gbase,
                                               int* __restrict__ eidx,
                                               int* __restrict__ rowptr,
                                               float* __restrict__ dinv, int n, int e) {
    __shared__ int cnt[NPB];
    __shared__ int sc[NPB];
    __shared__ int cur[NPB];
    int b = blockIdx.x;
    int node0 = b * NPB;
    int range = min(NPB, n - node0);
    int inbase = gbase[b];
    int m_b = gbase[b + 1] - inbase;
    if (threadIdx.x < NPB) cnt[threadIdx.x] = 0;
    __syncthreads();
    for (int j = threadIdx.x; j < m_b; j += 256)
        atomicAdd(&cnt[sorted[inbase + j] & (NPB - 1)], 1);
    __syncthreads();
    if (threadIdx.x < NPB) sc[threadIdx.x] = cnt[threadIdx.x];
    __syncthreads();
    for (int off = 1; off < NPB; off <<= 1) {
        int t = (threadIdx.x < NPB && threadIdx.x >= off) ? sc[threadIdx.x - off] : 0;
        __syncthreads();
        if (threadIdx.x < NPB) sc[threadIdx.x] += t;
        __syncthreads();
    }
    if (threadIdx.x < NPB) {
        int excl = inbase + sc[threadIdx.x] - cnt[threadIdx.x];
        cur[threadIdx.x] = excl;
        if (threadIdx.x < range) {
            rowptr[node0 + threadIdx.x] = excl;
            dinv[node0 + threadIdx.x] = rsqrtf((float)(cnt[threadIdx.x] + 1));
        }
    }
    __syncthreads();
    for (int j = threadIdx.x; j < m_b; j += 256) {
        int v = sorted[inbase + j];
        int pos = atomicAdd(&cur[v & (NPB - 1)], 1);
        eidx[pos] = v >> BSH;
    }
    if (b == 0 && threadIdx.x == 0) rowptr[n] = e;
}

// ---------------- h' = (x @ W) * dinv[row], bf16 MFMA ----------------
__global__ __launch_bounds__(256) void k_gemm(const float* __restrict__ x,
                                              const float* __restrict__ W,
                                              const float* __restrict__ dinv,
                                              unsigned short* __restrict__ h, int n) {
    __shared__ unsigned short Xl[64 * LDK];
    __shared__ unsigned short Wl[64 * LDK];  // transposed: Wl[n][k]

    const int t = threadIdx.x;
    const int row0 = blockIdx.x * 64;

#pragma unroll
    for (int i = 0; i < 16; ++i) {
        int f = i * 256 + t;
        int k = f >> 4;
        int n4 = (f & 15) * 4;
        float4 v = ((const float4*)W)[f];
        Wl[(n4 + 0) * LDK + k] = f2bf(v.x);
        Wl[(n4 + 1) * LDK + k] = f2bf(v.y);
        Wl[(n4 + 2) * LDK + k] = f2bf(v.z);
        Wl[(n4 + 3) * LDK + k] = f2bf(v.w);
    }
#pragma unroll
    for (int i = 0; i < 16; ++i) {
        int f = i * 256 + t;
        int row = f >> 6;
        int c4 = f & 63;
        int gr = row0 + row;
        float4 v = (gr < n) ? ((const float4*)x)[(size_t)gr * 64 + c4]
                            : make_float4(0.f, 0.f, 0.f, 0.f);
        unsigned short* p = &Xl[row * LDK + c4 * 4];
        ushort4 o;
        o.x = f2bf(v.x); o.y = f2bf(v.y); o.z = f2bf(v.z); o.w = f2bf(v.w);
        *(ushort4*)p = o;
    }
    __syncthreads();

    const int lane = t & 63;
    const int w = t >> 6;
    const int m = lane & 15;
    const int q = lane >> 4;

    f32x4 acc[4];
#pragma unroll
    for (int nt = 0; nt < 4; ++nt) acc[nt] = (f32x4){0.f, 0.f, 0.f, 0.f};

#pragma unroll
    for (int ks = 0; ks < 8; ++ks) {
        bf16x8 A = *(const bf16x8*)&Xl[(16 * w + m) * LDK + ks * 32 + q * 8];
#pragma unroll
        for (int nt = 0; nt < 4; ++nt) {
            bf16x8 B = *(const bf16x8*)&Wl[(16 * nt + m) * LDK + ks * 32 + q * 8];
            acc[nt] = __builtin_amdgcn_mfma_f32_16x16x32_bf16(A, B, acc[nt], 0, 0, 0);
        }
    }

#pragma unroll
    for (int r = 0; r < 4; ++r) {
        int gr = row0 + 16 * w + q * 4 + r;
        if (gr < n) {
            float di = dinv[gr];
#pragma unroll
            for (int nt = 0; nt < 4; ++nt)
                h[(size_t)gr * C_OUT + nt * 16 + m] = f2bf(acc[nt][r] * di);
        }
    }
}

// ---------------- gather: 1 wave/node, 8 lanes/edge, uint4 (8 ch) per lane ----------------
// out[d] = dinv[d] * (sum_{s in N(d)} h'[s] + h'[d]) + b
__global__ __launch_bounds__(256) void k_gather(const int* __restrict__ rowptr,
                                                const int* __restrict__ eidx,
                                                const unsigned short* __restrict__ h,
                                                const float* __restrict__ dinv,
                                                const float* __restrict__ bias,
                                                float* __restrict__ out, int n) {
    int node = blockIdx.x * 4 + (threadIdx.x >> 6);
    if (node >= n) return;
    int lane = threadIdx.x & 63;
    int g = lane >> 3;          // edge slot 0..7
    int c8 = (lane & 7) * 8;    // channel base 0..56

    int beg = rowptr[node];
    int end = rowptr[node + 1];
    float a0 = 0.f, a1 = 0.f, a2 = 0.f, a3 = 0.f;
    float a4 = 0.f, a5 = 0.f, a6 = 0.f, a7 = 0.f;

    int j = beg;
    for (; j + 15 < end; j += 16) {
        int sa = eidx[j + g];
        int sb = eidx[j + 8 + g];
        uint4 ha = *(const uint4*)&h[(size_t)sa * C_OUT + c8];
        uint4 hb = *(const uint4*)&h[(size_t)sb * C_OUT + c8];
        a0 += bflo(ha.x); a1 += bfhi(ha.x); a2 += bflo(ha.y); a3 += bfhi(ha.y);
        a4 += bflo(ha.z); a5 += bfhi(ha.z); a6 += bflo(ha.w); a7 += bfhi(ha.w);
        a0 += bflo(hb.x); a1 += bfhi(hb.x); a2 += bflo(hb.y); a3 += bfhi(hb.y);
        a4 += bflo(hb.z); a5 += bfhi(hb.z); a6 += bflo(hb.w); a7 += bfhi(hb.w);
    }
    for (; j < end; j += 8) {
        int rem = end - j;
        int idx = j + ((g < rem) ? g : 0);
        int s = eidx[idx];
        float mq = (g < rem) ? 1.f : 0.f;
        uint4 hv = *(const uint4*)&h[(size_t)s * C_OUT + c8];
        a0 += bflo(hv.x) * mq; a1 += bfhi(hv.x) * mq;
        a2 += bflo(hv.y) * mq; a3 += bfhi(hv.y) * mq;
        a4 += bflo(hv.z) * mq; a5 += bfhi(hv.z) * mq;
        a6 += bflo(hv.w) * mq; a7 += bfhi(hv.w) * mq;
    }
    // butterfly over the 8 edge slots (xor bits 3,4,5) -> every lane holds totals
#pragma unroll
    for (int off = 8; off < 64; off <<= 1) {
        a0 += __shfl_xor(a0, off, 64); a1 += __shfl_xor(a1, off, 64);
        a2 += __shfl_xor(a2, off, 64); a3 += __shfl_xor(a3, off, 64);
        a4 += __shfl_xor(a4, off, 64); a5 += __shfl_xor(a5, off, 64);
        a6 += __shfl_xor(a6, off, 64); a7 += __shfl_xor(a7, off, 64);
    }
    if (g == 0) {
        float di = dinv[node];
        uint4 sv = *(const uint4*)&h[(size_t)node * C_OUT + c8];
        float4 b0 = *(const float4*)&bias[c8];
        float4 b1 = *(const float4*)&bias[c8 + 4];
        float4 o0, o1;
        o0.x = (a0 + bflo(sv.x)) * di + b0.x;
        o0.y = (a1 + bfhi(sv.x)) * di + b0.y;
        o0.z = (a2 + bflo(sv.y)) * di + b0.z;
        o0.w = (a3 + bfhi(sv.y)) * di + b0.w;
        o1.x = (a4 + bflo(sv.z)) * di + b1.x;
        o1.y = (a5 + bfhi(sv.z)) * di + b1.y;
        o1.z = (a6 + bflo(sv.w)) * di + b1.z;
        o1.w = (a7 + bfhi(sv.w)) * di + b1.w;
        *(float4*)&out[(size_t)node * C_OUT + c8] = o0;
        *(float4*)&out[(size_t)node * C_OUT + c8 + 4] = o1;
    }
}

extern "C" void kernel_launch(void* const* d_in, const int* in_sizes, int n_in,
                              void* d_out, int out_size, void* d_ws, size_t ws_size,
                              hipStream_t stream) {
    const float* x = (const float*)d_in[0];
    const int* ei = (const int*)d_in[1];
    const float* W = (const float*)d_in[2];
    const float* bias = (const float*)d_in[3];
    float* out = (float*)d_out;

    const int n = in_sizes[0] / C_IN;  // 100000
    const int e = in_sizes[1] / 2;     // 3200000
    const int* src = ei;
    const int* dst = ei + e;

    const int nbin = (e + CHUNK - 1) / CHUNK;   // 782
    const int nbuck = (n + NPB - 1) / NPB;      // 782

    char* w = (char*)d_ws;
    unsigned short* h = (unsigned short*)w;  w += (size_t)n * C_OUT * 2;   // 12.8 MB
    int* sorted = (int*)w;                   w += (size_t)e * 4;           // 12.8 MB
    int* eidx = (int*)w;                     w += (size_t)e * 4;           // 12.8 MB
    float* dinv = (float*)w;                 w += (size_t)n * 4;
    int* rowptr = (int*)w;                   w += (size_t)(n + 1) * 4;
    int* table = (int*)w;                    w += (size_t)nbin * NB * 4;   // 3.2 MB
    int* tot = (int*)w;                      w += NB * 4;
    int* gbase = (int*)w;                    w += (NB + 1) * 4;

    k_hist2<<<nbin, 256, 0, stream>>>(dst, table, e);
    kA2<<<NB, 256, 0, stream>>>(table, tot, nbin);
    kB<<<1, 1024, 0, stream>>>(tot, gbase, e);
    k_bin2<<<nbin, 256, 0, stream>>>(src, dst, table, gbase, sorted, e);
    k_sort2<<<nbuck, 256, 0, stream>>>(sorted, gbase, eidx, rowptr, dinv, n, e);
    k_gemm<<<(n + 63) / 64, 256, 0, stream>>>(x, W, dinv, h, n);
    k_gather<<<(n + 3) / 4, 256, 0, stream>>>(rowptr, eidx, h, dinv, bias, out, n);
}

// Round 13
// 350.514 us; speedup vs baseline: 1.1046x; 1.0401x over previous
//
#include <hip/hip_runtime.h>

#define C_IN 256
#define C_OUT 64
#define BSH 7                 // bucket = dst >> 7  (128 nodes/bucket)
#define NPB 128               // nodes per bucket
#define NB 1024               // max buckets (n <= 131072)
#define CHUNK 4096            // edges per binning block
#define ROWS 4                // table rows per thread in kA2 (256*4 >= nbin)
#define LDK 264               // padded row stride (ushorts): 256 + 8 -> 528 B

typedef short bf16x8 __attribute__((ext_vector_type(8)));
typedef float f32x4 __attribute__((ext_vector_type(4)));

__device__ __forceinline__ unsigned short f2bf(float f) {
    unsigned u = __builtin_bit_cast(unsigned, f);
    u = (u + 0x7FFFu + ((u >> 16) & 1u)) >> 16;
    return (unsigned short)u;
}
__device__ __forceinline__ float bflo(unsigned u) {
    return __builtin_bit_cast(float, u << 16);
}
__device__ __forceinline__ float bfhi(unsigned u) {
    return __builtin_bit_cast(float, u & 0xffff0000u);
}

// ---------------- one-shot: WT[n][k] = bf16(W[k][n]) ----------------
__global__ __launch_bounds__(256) void k_wt(const float* __restrict__ W,
                                            unsigned short* __restrict__ WT) {
#pragma unroll
    for (int i = 0; i < 16; ++i) {
        int f = i * 256 + threadIdx.x;   // float4 id over 256x64
        int k = f >> 4;
        int n4 = (f & 15) * 4;
        float4 v = ((const float4*)W)[f];
        WT[(n4 + 0) * 256 + k] = f2bf(v.x);
        WT[(n4 + 1) * 256 + k] = f2bf(v.y);
        WT[(n4 + 2) * 256 + k] = f2bf(v.z);
        WT[(n4 + 3) * 256 + k] = f2bf(v.w);
    }
}

// ---------------- per-(block,bucket) histogram table ----------------
__global__ __launch_bounds__(1024) void k_hist2(const int* __restrict__ dst,
                                                int* __restrict__ table, int e) {
    __shared__ int cnt[NB];
    if (threadIdx.x < NB) cnt[threadIdx.x] = 0;
    __syncthreads();
    int b0 = blockIdx.x * CHUNK;
#pragma unroll
    for (int k = 0; k < CHUNK / 1024; ++k) {
        int i = b0 + k * 1024 + threadIdx.x;
        if (i < e) atomicAdd(&cnt[dst[i] >> BSH], 1);
    }
    __syncthreads();
    if (threadIdx.x < NB) table[(size_t)blockIdx.x * NB + threadIdx.x] = cnt[threadIdx.x];
}

// ---------------- column-wise exclusive scan: one block per bucket ----------------
__global__ __launch_bounds__(256) void kA2(int* __restrict__ table,
                                           int* __restrict__ tot, int nbin) {
    __shared__ int part[256];
    int bucket = blockIdx.x;
    int t = threadIdx.x;
    int v[ROWS];
    int s = 0;
#pragma unroll
    for (int i = 0; i < ROWS; ++i) {
        int r = t * ROWS + i;
        int x = (r < nbin) ? table[(size_t)r * NB + bucket] : 0;
        v[i] = s;
        s += x;
    }
    part[t] = s;
    __syncthreads();
    for (int off = 1; off < 256; off <<= 1) {
        int u = (t >= off) ? part[t - off] : 0;
        __syncthreads();
        part[t] += u;
        __syncthreads();
    }
    int base = part[t] - s;  // exclusive over threads
#pragma unroll
    for (int i = 0; i < ROWS; ++i) {
        int r = t * ROWS + i;
        if (r < nbin) table[(size_t)r * NB + bucket] = v[i] + base;
    }
    if (t == 255) tot[bucket] = part[255];
}

// ---------------- bucket totals -> compact gbase ----------------
__global__ __launch_bounds__(1024) void kB(const int* __restrict__ tot,
                                           int* __restrict__ gbase, int e) {
    __shared__ int l[NB];
    int t = threadIdx.x;
    int v = tot[t];
    l[t] = v;
    __syncthreads();
    for (int off = 1; off < NB; off <<= 1) {
        int u = (t >= off) ? l[t - off] : 0;
        __syncthreads();
        l[t] += u;
        __syncthreads();
    }
    gbase[t] = l[t] - v;  // exclusive
    if (t == NB - 1) gbase[NB] = e;
}

// ---------------- single-pass atomic-free multisplit (1024 thr) ----------------
__global__ __launch_bounds__(1024) void k_bin2(const int* __restrict__ src,
                                               const int* __restrict__ dst,
                                               const int* __restrict__ table,
                                               const int* __restrict__ gbase,
                                               int* __restrict__ sorted, int e) {
    __shared__ int cur[NB];
    if (threadIdx.x < NB)
        cur[threadIdx.x] = table[(size_t)blockIdx.x * NB + threadIdx.x] + gbase[threadIdx.x];
    __syncthreads();
    int b0 = blockIdx.x * CHUNK;
#pragma unroll
    for (int k = 0; k < CHUNK / 1024; ++k) {
        int i = b0 + k * 1024 + threadIdx.x;
        if (i < e) {
            int d = dst[i];
            int bb = d >> BSH;
            int off = atomicAdd(&cur[bb], 1);
            sorted[off] = (src[i] << BSH) | (d & (NPB - 1));
        }
    }
}

// ---------------- in-bucket counting sort -> per-node CSR, plus dinv (512 thr) ----------------
__global__ __launch_bounds__(512) void k_sort2(const int* __restrict__ sorted,
                                               const int* __restrict__ gbase,
                                               int* __restrict__ eidx,
                                               int* __restrict__ rowptr,
                                               float* __restrict__ dinv, int n, int e) {
    __shared__ int cnt[NPB];
    __shared__ int sc[NPB];
    __shared__ int cur[NPB];
    int b = blockIdx.x;
    int node0 = b * NPB;
    int range = min(NPB, n - node0);
    int inbase = gbase[b];
    int m_b = gbase[b + 1] - inbase;
    if (threadIdx.x < NPB) cnt[threadIdx.x] = 0;
    __syncthreads();
    for (int j = threadIdx.x; j < m_b; j += 512)
        atomicAdd(&cnt[sorted[inbase + j] & (NPB - 1)], 1);
    __syncthreads();
    if (threadIdx.x < NPB) sc[threadIdx.x] = cnt[threadIdx.x];
    __syncthreads();
    for (int off = 1; off < NPB; off <<= 1) {
        int t = (threadIdx.x < NPB && threadIdx.x >= off) ? sc[threadIdx.x - off] : 0;
        __syncthreads();
        if (threadIdx.x < NPB) sc[threadIdx.x] += t;
        __syncthreads();
    }
    if (threadIdx.x < NPB) {
        int excl = inbase + sc[threadIdx.x] - cnt[threadIdx.x];
        cur[threadIdx.x] = excl;
        if (threadIdx.x < range) {
            rowptr[node0 + threadIdx.x] = excl;
            dinv[node0 + threadIdx.x] = rsqrtf((float)(cnt[threadIdx.x] + 1));
        }
    }
    __syncthreads();
    for (int j = threadIdx.x; j < m_b; j += 512) {
        int v = sorted[inbase + j];
        int pos = atomicAdd(&cur[v & (NPB - 1)], 1);
        eidx[pos] = v >> BSH;
    }
    if (b == 0 && threadIdx.x == 0) rowptr[n] = e;
}

// ---------------- h' = (x @ W) * dinv[row], bf16 MFMA ----------------
__global__ __launch_bounds__(256) void k_gemm(const float* __restrict__ x,
                                              const unsigned short* __restrict__ WT,
                                              const float* __restrict__ dinv,
                                              unsigned short* __restrict__ h, int n) {
    __shared__ unsigned short Xl[64 * LDK];
    __shared__ unsigned short Wl[64 * LDK];  // Wl[n][k] bf16

    const int t = threadIdx.x;
    const int row0 = blockIdx.x * 64;

    // stage WT -> Wl: coalesced uint4 copy, conflict-free
#pragma unroll
    for (int i = 0; i < 8; ++i) {
        int f = i * 256 + t;            // uint4 id over 64x256 ushorts
        int row = f >> 5;               // 32 uint4 per row
        int c = f & 31;
        uint4 v = ((const uint4*)WT)[f];
        *(uint4*)&Wl[row * LDK + c * 8] = v;
    }
    // stage X tile (64 rows x 256 k), coalesced, fp32 -> bf16
#pragma unroll
    for (int i = 0; i < 16; ++i) {
        int f = i * 256 + t;
        int row = f >> 6;
        int c4 = f & 63;
        int gr = row0 + row;
        float4 v = (gr < n) ? ((const float4*)x)[(size_t)gr * 64 + c4]
                            : make_float4(0.f, 0.f, 0.f, 0.f);
        ushort4 o;
        o.x = f2bf(v.x); o.y = f2bf(v.y); o.z = f2bf(v.z); o.w = f2bf(v.w);
        *(ushort4*)&Xl[row * LDK + c4 * 4] = o;
    }
    __syncthreads();

    const int lane = t & 63;
    const int w = t >> 6;
    const int m = lane & 15;
    const int q = lane >> 4;

    f32x4 acc[4];
#pragma unroll
    for (int nt = 0; nt < 4; ++nt) acc[nt] = (f32x4){0.f, 0.f, 0.f, 0.f};

#pragma unroll
    for (int ks = 0; ks < 8; ++ks) {
        bf16x8 A = *(const bf16x8*)&Xl[(16 * w + m) * LDK + ks * 32 + q * 8];
#pragma unroll
        for (int nt = 0; nt < 4; ++nt) {
            bf16x8 B = *(const bf16x8*)&Wl[(16 * nt + m) * LDK + ks * 32 + q * 8];
            acc[nt] = __builtin_amdgcn_mfma_f32_16x16x32_bf16(A, B, acc[nt], 0, 0, 0);
        }
    }

#pragma unroll
    for (int r = 0; r < 4; ++r) {
        int gr = row0 + 16 * w + q * 4 + r;
        if (gr < n) {
            float di = dinv[gr];
#pragma unroll
            for (int nt = 0; nt < 4; ++nt)
                h[(size_t)gr * C_OUT + nt * 16 + m] = f2bf(acc[nt][r] * di);
        }
    }
}

// ---------------- gather: 1 wave/node, 8 lanes/edge, uint4 (8 ch) per lane ----------------
// out[d] = dinv[d] * (sum_{s in N(d)} h'[s] + h'[d]) + b
__global__ __launch_bounds__(256) void k_gather(const int* __restrict__ rowptr,
                                                const int* __restrict__ eidx,
                                                const unsigned short* __restrict__ h,
                                                const float* __restrict__ dinv,
                                                const float* __restrict__ bias,
                                                float* __restrict__ out, int n) {
    int node = blockIdx.x * 4 + (threadIdx.x >> 6);
    if (node >= n) return;
    int lane = threadIdx.x & 63;
    int g = lane >> 3;          // edge slot 0..7
    int c8 = (lane & 7) * 8;    // channel base 0..56

    int beg = rowptr[node];
    int end = rowptr[node + 1];
    float a0 = 0.f, a1 = 0.f, a2 = 0.f, a3 = 0.f;
    float a4 = 0.f, a5 = 0.f, a6 = 0.f, a7 = 0.f;

    int j = beg;
    for (; j + 15 < end; j += 16) {
        int sa = eidx[j + g];
        int sb = eidx[j + 8 + g];
        uint4 ha = *(const uint4*)&h[(size_t)sa * C_OUT + c8];
        uint4 hb = *(const uint4*)&h[(size_t)sb * C_OUT + c8];
        a0 += bflo(ha.x); a1 += bfhi(ha.x); a2 += bflo(ha.y); a3 += bfhi(ha.y);
        a4 += bflo(ha.z); a5 += bfhi(ha.z); a6 += bflo(ha.w); a7 += bfhi(ha.w);
        a0 += bflo(hb.x); a1 += bfhi(hb.x); a2 += bflo(hb.y); a3 += bfhi(hb.y);
        a4 += bflo(hb.z); a5 += bfhi(hb.z); a6 += bflo(hb.w); a7 += bfhi(hb.w);
    }
    for (; j < end; j += 8) {
        int rem = end - j;
        int idx = j + ((g < rem) ? g : 0);
        int s = eidx[idx];
        float mq = (g < rem) ? 1.f : 0.f;
        uint4 hv = *(const uint4*)&h[(size_t)s * C_OUT + c8];
        a0 += bflo(hv.x) * mq; a1 += bfhi(hv.x) * mq;
        a2 += bflo(hv.y) * mq; a3 += bfhi(hv.y) * mq;
        a4 += bflo(hv.z) * mq; a5 += bfhi(hv.z) * mq;
        a6 += bflo(hv.w) * mq; a7 += bfhi(hv.w) * mq;
    }
#pragma unroll
    for (int off = 8; off < 64; off <<= 1) {
        a0 += __shfl_xor(a0, off, 64); a1 += __shfl_xor(a1, off, 64);
        a2 += __shfl_xor(a2, off, 64); a3 += __shfl_xor(a3, off, 64);
        a4 += __shfl_xor(a4, off, 64); a5 += __shfl_xor(a5, off, 64);
        a6 += __shfl_xor(a6, off, 64); a7 += __shfl_xor(a7, off, 64);
    }
    if (g == 0) {
        float di = dinv[node];
        uint4 sv = *(const uint4*)&h[(size_t)node * C_OUT + c8];
        float4 b0 = *(const float4*)&bias[c8];
        float4 b1 = *(const float4*)&bias[c8 + 4];
        float4 o0, o1;
        o0.x = (a0 + bflo(sv.x)) * di + b0.x;
        o0.y = (a1 + bfhi(sv.x)) * di + b0.y;
        o0.z = (a2 + bflo(sv.y)) * di + b0.z;
        o0.w = (a3 + bfhi(sv.y)) * di + b0.w;
        o1.x = (a4 + bflo(sv.z)) * di + b1.x;
        o1.y = (a5 + bfhi(sv.z)) * di + b1.y;
        o1.z = (a6 + bflo(sv.w)) * di + b1.z;
        o1.w = (a7 + bfhi(sv.w)) * di + b1.w;
        *(float4*)&out[(size_t)node * C_OUT + c8] = o0;
        *(float4*)&out[(size_t)node * C_OUT + c8 + 4] = o1;
    }
}

extern "C" void kernel_launch(void* const* d_in, const int* in_sizes, int n_in,
                              void* d_out, int out_size, void* d_ws, size_t ws_size,
                              hipStream_t stream) {
    const float* x = (const float*)d_in[0];
    const int* ei = (const int*)d_in[1];
    const float* W = (const float*)d_in[2];
    const float* bias = (const float*)d_in[3];
    float* out = (float*)d_out;

    const int n = in_sizes[0] / C_IN;  // 100000
    const int e = in_sizes[1] / 2;     // 3200000
    const int* src = ei;
    const int* dst = ei + e;

    const int nbin = (e + CHUNK - 1) / CHUNK;   // 782
    const int nbuck = (n + NPB - 1) / NPB;      // 782

    char* w = (char*)d_ws;
    unsigned short* h = (unsigned short*)w;  w += (size_t)n * C_OUT * 2;   // 12.8 MB
    int* sorted = (int*)w;                   w += (size_t)e * 4;           // 12.8 MB
    int* eidx = (int*)w;                     w += (size_t)e * 4;           // 12.8 MB
    float* dinv = (float*)w;                 w += (size_t)n * 4;
    int* rowptr = (int*)w;                   w += (size_t)(n + 1) * 4;
    int* table = (int*)w;                    w += (size_t)nbin * NB * 4;   // 3.2 MB
    int* tot = (int*)w;                      w += NB * 4;
    int* gbase = (int*)w;                    w += (NB + 1) * 4;
    unsigned short* WT = (unsigned short*)w; w += (size_t)C_OUT * C_IN * 2; // 32 KB

    k_wt<<<1, 256, 0, stream>>>(W, WT);
    k_hist2<<<nbin, 1024, 0, stream>>>(dst, table, e);
    kA2<<<NB, 256, 0, stream>>>(table, tot, nbin);
    kB<<<1, 1024, 0, stream>>>(tot, gbase, e);
    k_bin2<<<nbin, 1024, 0, stream>>>(src, dst, table, gbase, sorted, e);
    k_sort2<<<nbuck, 512, 0, stream>>>(sorted, gbase, eidx, rowptr, dinv, n, e);
    k_gemm<<<(n + 63) / 64, 256, 0, stream>>>(x, WT, dinv, h, n);
    k_gather<<<(n + 3) / 4, 256, 0, stream>>>(rowptr, eidx, h, dinv, bias, out, n);
}